// Round 1
// baseline (819.190 us; speedup 1.0000x reference)
//
#include <hip/hip_runtime.h>
#include <hip/hip_bf16.h>

#define DIM 2048
#define NTOK 65536

// Extract lam[d] = -|W[d,d]| into workspace (8 KiB).
__global__ void diag_extract_kernel(const float* __restrict__ W,
                                    float* __restrict__ lam) {
    int d = blockIdx.x * blockDim.x + threadIdx.x;
    if (d < DIM) {
        lam[d] = -fabsf(W[(size_t)d * (DIM + 1)]);
    }
}

// out[n,d] = x[n,d] * lam[d], one float4 per thread, fully coalesced.
__global__ __launch_bounds__(256) void diag_scale_kernel(
    const float4* __restrict__ x,
    const float4* __restrict__ lam4,   // DIM/4 = 512 float4s, L1/L2 resident
    float4* __restrict__ out,
    int n4) {
    int i = blockIdx.x * blockDim.x + threadIdx.x;
    if (i < n4) {
        float4 xv = x[i];
        float4 lv = lam4[i & (DIM / 4 - 1)];
        float4 o;
        o.x = xv.x * lv.x;
        o.y = xv.y * lv.y;
        o.z = xv.z * lv.z;
        o.w = xv.w * lv.w;
        out[i] = o;
    }
}

extern "C" void kernel_launch(void* const* d_in, const int* in_sizes, int n_in,
                              void* d_out, int out_size, void* d_ws, size_t ws_size,
                              hipStream_t stream) {
    const float* x = (const float*)d_in[0];
    const float* W = (const float*)d_in[1];
    float* out = (float*)d_out;
    float* lam = (float*)d_ws;  // 2048 floats = 8 KiB scratch

    // 1) extract diagonal
    diag_extract_kernel<<<(DIM + 255) / 256, 256, 0, stream>>>(W, lam);

    // 2) elementwise scale, float4-vectorized
    const int n4 = (NTOK * DIM) / 4;  // 33,554,432
    diag_scale_kernel<<<n4 / 256, 256, 0, stream>>>(
        (const float4*)x, (const float4*)lam, (float4*)out, n4);
}